// Round 1
// baseline (880.568 us; speedup 1.0000x reference)
//
#include <hip/hip_runtime.h>
#include <hip/hip_bf16.h>

// Problem dims (fixed by setup_inputs)
constexpr int BQ = 32;          // batch
constexpr int TT = 128;         // tokens
constexpr int DD = 13;          // depth
constexpr int E  = 1024;        // d_emb
constexpr int P  = 64;          // n_parts
constexpr int C  = 16;          // d_cap
constexpr int NC = 5;           // n_classes
constexpr int NI = TT * DD;     // 1664 input capsules (routing 1)
constexpr int NROWS = BQ * NI;  // 53248
constexpr int RB = 8;           // rows per block in k1

// ---------------------------------------------------------------------------
// sumfa[b] = sum_i fa[b,i] = 13 * sum_t mask[b,t]   (fa = sigmoid(logit(m)) = m)
__global__ void k_sumfa(const float* __restrict__ mask, float* __restrict__ sumfa)
{
    const int b = blockIdx.x, tid = threadIdx.x;   // 128 threads
    float v = mask[b * TT + tid];
#pragma unroll
    for (int off = 32; off > 0; off >>= 1) v += __shfl_xor(v, off);
    __shared__ float p2[2];
    if ((tid & 63) == 0) p2[tid >> 6] = v;
    __syncthreads();
    if (tid == 0) sumfa[b] = (float)DD * (p2[0] + p2[1]);
}

// ---------------------------------------------------------------------------
// K1: LayerNorm -> Linear(1024->64) -> Swish -> V = mu @ W1 + B1, store V.
// 8 rows per block, 256 threads (4 waves).
__global__ void k1_parts_v(const float* __restrict__ embs, const float* __restrict__ depth_emb,
                           const float* __restrict__ ln_w, const float* __restrict__ ln_b,
                           const float* __restrict__ dp_w, const float* __restrict__ dp_b,
                           const float* __restrict__ W1,  const float* __restrict__ B1,
                           float* __restrict__ V)
{
    __shared__ float xn[RB][E];    // 32 KB
    __shared__ float muL[RB][P];   // 2 KB
    const int tid = threadIdx.x;
    const int wave = tid >> 6, lane = tid & 63;
    const int row0 = blockIdx.x * RB;

    // Phase 1: LayerNorm. Each wave handles 2 rows (wave-local reductions only).
    for (int rr = 0; rr < 2; ++rr) {
        const int r = wave * 2 + rr;
        const int row = row0 + r;
        const int dd = row % DD;
        const float* xr = embs + (size_t)row * E;
        const float* de = depth_emb + (size_t)dd * E;
        float4 xv[4];
        float s = 0.f;
#pragma unroll
        for (int k = 0; k < 4; ++k) {
            const int e = 4 * lane + 256 * k;
            float4 a = *reinterpret_cast<const float4*>(xr + e);
            const float4 d4 = *reinterpret_cast<const float4*>(de + e);
            a.x += d4.x; a.y += d4.y; a.z += d4.z; a.w += d4.w;
            xv[k] = a;
            s += a.x + a.y + a.z + a.w;
        }
#pragma unroll
        for (int off = 32; off > 0; off >>= 1) s += __shfl_xor(s, off);
        const float mean = s * (1.f / E);
        float vs = 0.f;
#pragma unroll
        for (int k = 0; k < 4; ++k) {
            const float4 a = xv[k];
            const float dx = a.x - mean, dy = a.y - mean, dz = a.z - mean, dw = a.w - mean;
            vs += dx * dx + dy * dy + dz * dz + dw * dw;
        }
#pragma unroll
        for (int off = 32; off > 0; off >>= 1) vs += __shfl_xor(vs, off);
        const float rstd = rsqrtf(vs * (1.f / E) + 1e-5f);
#pragma unroll
        for (int k = 0; k < 4; ++k) {
            const int e = 4 * lane + 256 * k;
            const float4 a = xv[k];
            const float4 w4 = *reinterpret_cast<const float4*>(ln_w + e);
            const float4 b4 = *reinterpret_cast<const float4*>(ln_b + e);
            float4 o4;
            o4.x = (a.x - mean) * rstd * w4.x + b4.x;
            o4.y = (a.y - mean) * rstd * w4.y + b4.y;
            o4.z = (a.z - mean) * rstd * w4.z + b4.z;
            o4.w = (a.w - mean) * rstd * w4.w + b4.w;
            *reinterpret_cast<float4*>(&xn[r][e]) = o4;
        }
    }
    __syncthreads();

    // Phase 2: h = xn @ dp_w^T + dp_b ; mu = swish(h). thread = (p, eq).
    {
        const int p = tid >> 2, eq = tid & 3;
        float hacc[RB];
#pragma unroll
        for (int r = 0; r < RB; ++r) hacc[r] = 0.f;
        const float* wp = dp_w + (size_t)p * E;
        for (int eb = 0; eb < E; eb += 16) {
            const float4 w4 = *reinterpret_cast<const float4*>(wp + eb + eq * 4);
#pragma unroll
            for (int r = 0; r < RB; ++r) {
                const float4 x4 = *reinterpret_cast<const float4*>(&xn[r][eb + eq * 4]);
                hacc[r] += w4.x * x4.x + w4.y * x4.y + w4.z * x4.z + w4.w * x4.w;
            }
        }
#pragma unroll
        for (int r = 0; r < RB; ++r) {
            float v = hacc[r];
            v += __shfl_xor(v, 1);
            v += __shfl_xor(v, 2);
            if (eq == 0) {
                const float h = v + dp_b[p];
                muL[r][p] = h / (1.f + __expf(-h));   // swish
            }
        }
    }
    __syncthreads();

    // Phase 3: V[r][j][h] = mu[r][:] @ W1[j][:][h] + B1[j][h]. thread = (j, hq).
    {
        const int j = tid >> 2, hq = tid & 3;
        float4 vacc[RB];
        const float4 b4 = *reinterpret_cast<const float4*>(B1 + j * C + hq * 4);
#pragma unroll
        for (int r = 0; r < RB; ++r) vacc[r] = b4;
        const float* w1p = W1 + ((size_t)j * P) * C + hq * 4;   // W1[j][d][h]
        for (int d = 0; d < P; ++d) {
            const float4 w4 = *reinterpret_cast<const float4*>(w1p + (size_t)d * C);
#pragma unroll
            for (int r = 0; r < RB; ++r) {
                const float m = muL[r][d];
                vacc[r].x += m * w4.x; vacc[r].y += m * w4.y;
                vacc[r].z += m * w4.z; vacc[r].w += m * w4.w;
            }
        }
#pragma unroll
        for (int r = 0; r < RB; ++r) {
            const size_t row = (size_t)(row0 + r);
            *reinterpret_cast<float4*>(V + (row * P + j) * C + hq * 4) = vacc[r];
        }
    }
}

// ---------------------------------------------------------------------------
// K2: one routing-1 iteration pass over V. Block = (b, tile of 64 i); wave
// lane = j (64 out-capsules). E-step quad + wave softmax; accumulate
// D = sum fa*R, Smu = sum D*V, SV2 = sum D*V^2 (block-reduced in LDS, then
// global atomics).
__global__ void k2_pass(const float* __restrict__ V, const float* __restrict__ mask,
                        const float* __restrict__ muo, const float* __restrict__ isg,
                        const float* __restrict__ biasv, float* __restrict__ Smu,
                        float* __restrict__ SV2, float* __restrict__ Dsum, const int it)
{
    __shared__ float lacc[P][34];   // [j][0..15]=Smu, [16..31]=SV2, [32]=Dsum
    const int tid = threadIdx.x;
    const int wave = tid >> 6, j = tid & 63;
    const int b = blockIdx.x / (NI / 64);
    const int tile = blockIdx.x % (NI / 64);

    for (int k = tid; k < P * 34; k += 256) (&lacc[0][0])[k] = 0.f;

    float mo[16], iv[16];
    float bj = 0.f;
    if (it > 0) {
        const float4* mp = reinterpret_cast<const float4*>(muo + ((size_t)b * P + j) * C);
        const float4* ip = reinterpret_cast<const float4*>(isg + ((size_t)b * P + j) * C);
#pragma unroll
        for (int k = 0; k < 4; ++k) {
            const float4 m4 = mp[k]; const float4 i4 = ip[k];
            mo[k * 4 + 0] = m4.x; mo[k * 4 + 1] = m4.y; mo[k * 4 + 2] = m4.z; mo[k * 4 + 3] = m4.w;
            iv[k * 4 + 0] = i4.x; iv[k * 4 + 1] = i4.y; iv[k * 4 + 2] = i4.z; iv[k * 4 + 3] = i4.w;
        }
        bj = biasv[(size_t)b * P + j];
    }

    float dsum = 0.f;
    float smuA[16], sv2A[16];
#pragma unroll
    for (int h = 0; h < 16; ++h) { smuA[h] = 0.f; sv2A[h] = 0.f; }

    __syncthreads();

    for (int s = 0; s < 16; ++s) {
        const int i = tile * 64 + wave * 16 + s;
        const float4* vp = reinterpret_cast<const float4*>(V + (((size_t)b * NI + i) * P + j) * C);
        float va[16];
        {
            const float4 t0 = vp[0], t1 = vp[1], t2 = vp[2], t3 = vp[3];
            va[0] = t0.x; va[1] = t0.y; va[2]  = t0.z; va[3]  = t0.w;
            va[4] = t1.x; va[5] = t1.y; va[6]  = t1.z; va[7]  = t1.w;
            va[8] = t2.x; va[9] = t2.y; va[10] = t2.z; va[11] = t2.w;
            va[12] = t3.x; va[13] = t3.y; va[14] = t3.z; va[15] = t3.w;
        }
        float R;
        if (it > 0) {
            float q = 0.f;
#pragma unroll
            for (int h = 0; h < 16; ++h) { const float d = va[h] - mo[h]; q += d * d * iv[h]; }
            const float sc = bj - q;
            float m = sc;
#pragma unroll
            for (int off = 32; off > 0; off >>= 1) m = fmaxf(m, __shfl_xor(m, off));
            const float e = __expf(sc - m);
            float sum = e;
#pragma unroll
            for (int off = 32; off > 0; off >>= 1) sum += __shfl_xor(sum, off);
            R = e / sum;
        } else {
            R = 1.f / 64.f;
        }
        const float fa = mask[b * TT + i / DD];   // fa = sigmoid(logit(mask)) = mask
        const float w = fa * R;
        dsum += w;
#pragma unroll
        for (int h = 0; h < 16; ++h) {
            smuA[h] += w * va[h];
            sv2A[h] += w * va[h] * va[h];
        }
    }

#pragma unroll
    for (int h = 0; h < 16; ++h) {
        atomicAdd(&lacc[j][h], smuA[h]);
        atomicAdd(&lacc[j][16 + h], sv2A[h]);
    }
    atomicAdd(&lacc[j][32], dsum);
    __syncthreads();

    for (int k = tid; k < P * 33; k += 256) {
        const int jj = k / 33, r = k % 33;
        const float v = lacc[jj][r];
        if (r < 16)      atomicAdd(&Smu[((size_t)b * P + jj) * C + r], v);
        else if (r < 32) atomicAdd(&SV2[((size_t)b * P + jj) * C + (r - 16)], v);
        else             atomicAdd(&Dsum[(size_t)b * P + jj], v);
    }
}

// ---------------------------------------------------------------------------
// K2f: finalize one routing-1 iteration: mu_out, inv2sig, a_out,
// bias = logsig(a_out) - 0.5*sum_h log sig2. One thread per (b,j).
__global__ void k2f(const float* __restrict__ Smu, const float* __restrict__ SV2,
                    const float* __restrict__ Dsum, const float* __restrict__ sumfa,
                    const float* __restrict__ bu, const float* __restrict__ bi,
                    float* __restrict__ muo, float* __restrict__ isg,
                    float* __restrict__ biasv, float* __restrict__ a1)
{
    const int t = blockIdx.x * blockDim.x + threadIdx.x;
    if (t >= BQ * P) return;
    const int b = t / P, j = t % P;
    const float ds = Dsum[t];
    const float inv = 1.f / ds;
    const float ao = bu[j] * ds - bi[j] * (sumfa[b] - ds);
    a1[t] = ao;
    const float lsg = (ao < 0.f) ? (ao - log1pf(__expf(ao))) : (-log1pf(__expf(-ao)));
    float sumlog = 0.f;
#pragma unroll
    for (int h = 0; h < C; ++h) {
        const float m = Smu[t * C + h] * inv;
        const float s2 = fmaxf(SV2[t * C + h] * inv - m * m, 0.f) + 1e-5f;
        muo[t * C + h] = m;
        isg[t * C + h] = 0.5f / s2;
        sumlog += logf(s2);
    }
    biasv[t] = lsg - 0.5f * sumlog;
}

// ---------------------------------------------------------------------------
// K3: routing 2 (n_i=64, n_o=5, d=16) entirely inside one block per batch.
__global__ void k3_routing2(const float* __restrict__ muo, const float* __restrict__ a1,
                            const float* __restrict__ W2, const float* __restrict__ B2,
                            const float* __restrict__ bu2, const float* __restrict__ bi2,
                            float* __restrict__ out)
{
    __shared__ float mu1L[P][C];
    __shared__ float faL[P];
    __shared__ float V2L[P][NC][C];
    __shared__ float RL[P][NC];
    __shared__ float mu2L[NC][C];
    __shared__ float s2L[NC][C];
    __shared__ float isL[NC][C];
    __shared__ float dsL[NC];
    __shared__ float biasL[NC];
    __shared__ float a2L[NC];
    __shared__ float sumfa2s;
    const int b = blockIdx.x, tid = threadIdx.x;

    for (int k = tid; k < P * C; k += 256) (&mu1L[0][0])[k] = muo[(size_t)b * P * C + k];
    if (tid < P) {
        const float a = a1[(size_t)b * P + tid];
        faL[tid] = 1.f / (1.f + __expf(-a));
    }
    __syncthreads();
    if (tid == 0) {
        float s = 0.f;
        for (int i = 0; i < P; ++i) s += faL[i];
        sumfa2s = s;
    }
    // V2[i][j][h] = mu1[i][:] @ W2[i][j][:][h] + B2[j][h]
    {
        const int i = tid >> 2, hq = tid & 3;
        for (int jj = 0; jj < NC; ++jj) {
            float4 acc = *reinterpret_cast<const float4*>(B2 + jj * C + hq * 4);
            const float* wp = W2 + ((size_t)(i * NC + jj) * C) * C + hq * 4;
#pragma unroll
            for (int d = 0; d < C; ++d) {
                const float m = mu1L[i][d];
                const float4 w4 = *reinterpret_cast<const float4*>(wp + d * C);
                acc.x += m * w4.x; acc.y += m * w4.y; acc.z += m * w4.z; acc.w += m * w4.w;
            }
            *reinterpret_cast<float4*>(&V2L[i][jj][hq * 4]) = acc;
        }
    }
    __syncthreads();

    for (int it = 0; it < 3; ++it) {
        if (tid < P) {
            const int i = tid;
            if (it == 0) {
#pragma unroll
                for (int jj = 0; jj < NC; ++jj) RL[i][jj] = 1.f / NC;
            } else {
                float sc[NC];
                float m = -3.4e38f;
#pragma unroll
                for (int jj = 0; jj < NC; ++jj) {
                    float q = 0.f;
#pragma unroll
                    for (int h = 0; h < C; ++h) {
                        const float d = V2L[i][jj][h] - mu2L[jj][h];
                        q += d * d * isL[jj][h];
                    }
                    sc[jj] = biasL[jj] - q;
                    m = fmaxf(m, sc[jj]);
                }
                float sum = 0.f;
#pragma unroll
                for (int jj = 0; jj < NC; ++jj) { sc[jj] = __expf(sc[jj] - m); sum += sc[jj]; }
                const float invs = 1.f / sum;
#pragma unroll
                for (int jj = 0; jj < NC; ++jj) RL[i][jj] = sc[jj] * invs;
            }
        }
        __syncthreads();
        if (tid < NC) {
            float ds = 0.f;
            for (int i = 0; i < P; ++i) ds += faL[i] * RL[i][tid];
            dsL[tid] = ds;
        }
        __syncthreads();
        if (tid < NC * C) {
            const int jj = tid / C, h = tid % C;
            float smu = 0.f, sv2 = 0.f;
            for (int i = 0; i < P; ++i) {
                const float w = faL[i] * RL[i][jj];
                const float v = V2L[i][jj][h];
                smu += w * v;
                sv2 += w * v * v;
            }
            const float inv = 1.f / dsL[jj];
            const float m = smu * inv;
            const float s2 = fmaxf(sv2 * inv - m * m, 0.f) + 1e-5f;
            mu2L[jj][h] = m;
            s2L[jj][h] = s2;
            isL[jj][h] = 0.5f / s2;
        }
        __syncthreads();
        if (tid < NC) {
            const float ds = dsL[tid];
            const float ao = bu2[tid] * ds - bi2[tid] * (sumfa2s - ds);
            a2L[tid] = ao;
            const float lsg = (ao < 0.f) ? (ao - log1pf(__expf(ao))) : (-log1pf(__expf(-ao)));
            float sl = 0.f;
#pragma unroll
            for (int h = 0; h < C; ++h) sl += logf(s2L[tid][h]);
            biasL[tid] = lsg - 0.5f * sl;
        }
        __syncthreads();
    }

    // outputs: a [32,5] | mu [32,5,1,16] | sig2 [32,5,1,16]
    if (tid < NC) out[(size_t)b * NC + tid] = a2L[tid];
    if (tid < NC * C) {
        const int jj = tid / C, h = tid % C;
        out[BQ * NC + ((size_t)b * NC + jj) * C + h] = mu2L[jj][h];
        out[BQ * NC + BQ * NC * C + ((size_t)b * NC + jj) * C + h] = s2L[jj][h];
    }
}

// ---------------------------------------------------------------------------
extern "C" void kernel_launch(void* const* d_in, const int* in_sizes, int n_in,
                              void* d_out, int out_size, void* d_ws, size_t ws_size,
                              hipStream_t stream)
{
    (void)in_sizes; (void)n_in; (void)out_size; (void)ws_size;
    const float* mask      = (const float*)d_in[0];
    const float* embs      = (const float*)d_in[1];
    const float* depth_emb = (const float*)d_in[2];
    const float* ln_w      = (const float*)d_in[3];
    const float* ln_b      = (const float*)d_in[4];
    const float* dp_w      = (const float*)d_in[5];
    const float* dp_b      = (const float*)d_in[6];
    const float* W1        = (const float*)d_in[7];
    const float* B1        = (const float*)d_in[8];
    const float* bu1       = (const float*)d_in[9];
    const float* bi1       = (const float*)d_in[10];
    const float* W2        = (const float*)d_in[11];
    const float* B2        = (const float*)d_in[12];
    const float* bu2       = (const float*)d_in[13];
    const float* bi2       = (const float*)d_in[14];
    float* out = (float*)d_out;

    // workspace layout (floats). Needs ~219 MB.
    float* ws = (float*)d_ws;
    size_t o = 0;
    float* V     = ws + o; o += (size_t)NROWS * P * C;   // 54,525,952
    float* Smu   = ws + o; o += (size_t)BQ * P * C;      // contiguous with SV2, Dsum (one memset)
    float* SV2   = ws + o; o += (size_t)BQ * P * C;
    float* Dsum  = ws + o; o += (size_t)BQ * P;
    float* muo   = ws + o; o += (size_t)BQ * P * C;
    float* isg   = ws + o; o += (size_t)BQ * P * C;
    float* biasv = ws + o; o += (size_t)BQ * P;
    float* a1    = ws + o; o += (size_t)BQ * P;
    float* sumfa = ws + o; o += (size_t)BQ;

    k_sumfa<<<BQ, 128, 0, stream>>>(mask, sumfa);
    k1_parts_v<<<NROWS / RB, 256, 0, stream>>>(embs, depth_emb, ln_w, ln_b,
                                               dp_w, dp_b, W1, B1, V);
    for (int it = 0; it < 3; ++it) {
        hipMemsetAsync(Smu, 0, (size_t)(2 * BQ * P * C + BQ * P) * sizeof(float), stream);
        k2_pass<<<BQ * (NI / 64), 256, 0, stream>>>(V, mask, muo, isg, biasv,
                                                    Smu, SV2, Dsum, it);
        k2f<<<(BQ * P) / 256, 256, 0, stream>>>(Smu, SV2, Dsum, sumfa, bu1, bi1,
                                                muo, isg, biasv, a1);
    }
    k3_routing2<<<BQ, 256, 0, stream>>>(muo, a1, W2, B2, bu2, bi2, out);
}